// Round 5
// baseline (3585.304 us; speedup 1.0000x reference)
//
#include <hip/hip_runtime.h>
#include <stdint.h>

#define NA 50000
#define NE 320000
#define AD 32
#define BD 64

// workspace layout (uint32 slots)
#define WS_FLAG   0
#define WS_COUNTS 16
#define WS_CURSOR (WS_COUNTS + NA)           // 50016
#define WS_OFFS   (WS_CURSOR + NA)           // 100016, NA+1 entries
#define WS_EIDS   150048                     // 8B-aligned; packed: uint2[NE], unpacked: u32[NE]
#define WS_NEED_PACKED   ((size_t)(WS_EIDS + 2 * NE) * 4)

__device__ __forceinline__ void load_pair(const void* p, int e, int mode, int& s, int& d){
  if (mode){ const int* q = (const int*)p; s = q[2*e]; d = q[2*e+1]; }
  else     { const long long* q = (const long long*)p; s = (int)q[2*e]; d = (int)q[2*e+1]; }
}

// detect int32 vs int64 pair_indices: int64 -> odd 32-bit words all 0 (values < 50000)
__global__ void k_detect(const void* pairs, uint32_t* ws){
  const uint32_t* w = (const uint32_t*)pairs;
  uint32_t x = 0;
  for (int i = threadIdx.x; i < 2048; i += 256) x |= w[2*i + 1];
  __shared__ uint32_t sh[256];
  sh[threadIdx.x] = x; __syncthreads();
  for (int s = 128; s > 0; s >>= 1){
    if (threadIdx.x < s) sh[threadIdx.x] |= sh[threadIdx.x + s];
    __syncthreads();
  }
  if (threadIdx.x == 0) ws[WS_FLAG] = (sh[0] != 0u) ? 1u : 0u;  // 1 = int32 mode
}

__global__ void k_hist(const void* pairs, uint32_t* ws){
  int e = blockIdx.x * 256 + threadIdx.x;
  if (e >= NE) return;
  int mode = (int)ws[WS_FLAG];
  int s, d; load_pair(pairs, e, mode, s, d);
  atomicAdd(&ws[WS_COUNTS + s], 1u);
}

// single-block exclusive scan of counts[NA] -> offs[NA+1]
__global__ void k_scan(uint32_t* ws){
  const uint32_t* counts = ws + WS_COUNTS;
  uint32_t* offs = ws + WS_OFFS;
  __shared__ uint32_t wsum[16];
  __shared__ uint32_t carrysh;
  const int tid = threadIdx.x; const int lane = tid & 63; const int wid = tid >> 6;
  if (tid == 0) carrysh = 0u;
  __syncthreads();
  for (int base = 0; base < NA; base += 8192){
    uint32_t v[8]; uint32_t tot = 0u;
    int i0 = base + tid * 8;
    #pragma unroll
    for (int j = 0; j < 8; ++j){ int i = i0 + j; v[j] = (i < NA) ? counts[i] : 0u; tot += v[j]; }
    uint32_t inc = tot;
    #pragma unroll
    for (int m = 1; m < 64; m <<= 1){ uint32_t t = __shfl_up(inc, m); if (lane >= m) inc += t; }
    if (lane == 63) wsum[wid] = inc;
    __syncthreads();
    if (wid == 0){
      uint32_t w = (lane < 16) ? wsum[lane] : 0u;
      #pragma unroll
      for (int m = 1; m < 16; m <<= 1){ uint32_t t = __shfl_up(w, m); if (lane >= m) w += t; }
      if (lane < 16) wsum[lane] = w;     // inclusive over waves
    }
    __syncthreads();
    uint32_t waveoff = (wid == 0) ? 0u : wsum[wid - 1];
    uint32_t run = carrysh + waveoff + (inc - tot);
    #pragma unroll
    for (int j = 0; j < 8; ++j){ int i = i0 + j; if (i < NA) offs[i] = run; run += v[j]; }
    __syncthreads();
    if (tid == 0) carrysh += wsum[15];
    __syncthreads();
  }
  if (tid == 0) offs[NA] = carrysh;
}

template<int PACKED>
__global__ void k_scatter(const void* pairs, uint32_t* ws){
  int e = blockIdx.x * 256 + threadIdx.x;
  if (e >= NE) return;
  int mode = (int)ws[WS_FLAG];
  int s, d; load_pair(pairs, e, mode, s, d);
  uint32_t p = atomicAdd(&ws[WS_CURSOR + s], 1u);
  uint32_t pos = ws[WS_OFFS + s] + p;
  if (PACKED) ((uint2*)(ws + WS_EIDS))[pos] = make_uint2((uint32_t)e, (uint32_t)d);
  else        ws[WS_EIDS + pos] = (uint32_t)e;
}

// R update: R[c][jj] += b_c * av.jj
#define RUP(Rm, c, bc) { Rm[c][0] += (bc)*av.x; Rm[c][1] += (bc)*av.y; \
                         Rm[c][2] += (bc)*av.z; Rm[c][3] += (bc)*av.w; }

// per-wave transpose-reduce of 8 acc values -> out[a*32 + half*16 + g*8 + 0..7]
#define EPI8(accArr, g, a)                                                      \
  { _Pragma("unroll")                                                           \
    for (int ii = 0; ii < 8; ++ii) myred[ii * 65 + lane] = accArr[(g) * 8 + ii];\
    const int ii2 = lane & 7, seg = lane >> 3;                                  \
    float p = 0.f;                                                              \
    _Pragma("unroll")                                                           \
    for (int t2 = 0; t2 < 8; ++t2) p += myred[ii2 * 65 + seg * 8 + t2];         \
    p += __shfl_xor(p, 8); p += __shfl_xor(p, 16); p += __shfl_xor(p, 32);      \
    if (lane < 8) out[(a) * 32 + half * 16 + (g) * 8 + lane] = p; }

// 256 threads = 4 waves, 2 atoms/wave, grid = NA/8 = 6250.
// lane = (kk = lane&7, jq = lane>>3). R[c][jj] = R[k = kk*8+c][j = jq*4+jj].
// Contraction split into two i-halves; per half, K half-chunks (8 rows x 512 cols,
// 16 KB) staged in LDS with XOR swizzle (^ slot*8 in float4 units).
__launch_bounds__(256, 2)
__global__ void k_main(const float* __restrict__ atoms, const float* __restrict__ bonds,
                       const void* __restrict__ pairs, const float* __restrict__ Kg,
                       const float* __restrict__ bias, float* __restrict__ out,
                       const uint32_t* __restrict__ ws, int packed){
  __shared__ float Ksh[8 * 512];        // 16 KB
  __shared__ float red[4 * 520];        // per-wave transpose scratch

  const int tid  = threadIdx.x;
  const int lane = tid & 63;
  const int wid  = tid >> 6;            // 0..3
  const int kk   = lane & 7;
  const int jq   = lane >> 3;           // 0..7
  const int mode = (int)ws[WS_FLAG];
  const uint32_t* offs = ws + WS_OFFS;

  const int a0 = blockIdx.x * 8 + wid * 2;
  const int a1 = a0 + 1;

  float R0[8][4], R1[8][4];
  #pragma unroll
  for (int c = 0; c < 8; ++c)
    #pragma unroll
    for (int j = 0; j < 4; ++j){ R0[c][j] = 0.f; R1[c][j] = 0.f; }
  float4 S0 = make_float4(0.f,0.f,0.f,0.f);
  float4 S1 = make_float4(0.f,0.f,0.f,0.f);

  // ---- R/S accumulation: atom0 then atom1 (no array-of-R indirection) ----
  {
    const uint32_t beg = offs[a0];
    const uint32_t n   = offs[a0 + 1] - beg;
    uint32_t e_nxt = 0, d_nxt = 0;
    if (n){
      if (packed){ uint2 ed = ((const uint2*)(ws + WS_EIDS))[beg]; e_nxt = ed.x; d_nxt = ed.y; }
      else { e_nxt = ws[WS_EIDS + beg]; int s_, d_; load_pair(pairs, (int)e_nxt, mode, s_, d_); d_nxt = (uint32_t)d_; }
    }
    for (uint32_t t = 0; t < n; ++t){
      const uint32_t e = e_nxt, d = d_nxt;
      if (t + 1 < n){
        if (packed){ uint2 ed = ((const uint2*)(ws + WS_EIDS))[beg + t + 1]; e_nxt = ed.x; d_nxt = ed.y; }
        else { e_nxt = ws[WS_EIDS + beg + t + 1]; int s_, d_; load_pair(pairs, (int)e_nxt, mode, s_, d_); d_nxt = (uint32_t)d_; }
      }
      const float4 av  = *(const float4*)&atoms[d * AD + jq * 4];
      const float4 b0v = *(const float4*)&bonds[e * BD + kk * 8];
      const float4 b1v = *(const float4*)&bonds[e * BD + kk * 8 + 4];
      RUP(R0, 0, b0v.x) RUP(R0, 1, b0v.y) RUP(R0, 2, b0v.z) RUP(R0, 3, b0v.w)
      RUP(R0, 4, b1v.x) RUP(R0, 5, b1v.y) RUP(R0, 6, b1v.z) RUP(R0, 7, b1v.w)
      if (kk == 0){ S0.x += av.x; S0.y += av.y; S0.z += av.z; S0.w += av.w; }
    }
  }
  {
    const uint32_t beg = offs[a1];
    const uint32_t n   = offs[a1 + 1] - beg;
    uint32_t e_nxt = 0, d_nxt = 0;
    if (n){
      if (packed){ uint2 ed = ((const uint2*)(ws + WS_EIDS))[beg]; e_nxt = ed.x; d_nxt = ed.y; }
      else { e_nxt = ws[WS_EIDS + beg]; int s_, d_; load_pair(pairs, (int)e_nxt, mode, s_, d_); d_nxt = (uint32_t)d_; }
    }
    for (uint32_t t = 0; t < n; ++t){
      const uint32_t e = e_nxt, d = d_nxt;
      if (t + 1 < n){
        if (packed){ uint2 ed = ((const uint2*)(ws + WS_EIDS))[beg + t + 1]; e_nxt = ed.x; d_nxt = ed.y; }
        else { e_nxt = ws[WS_EIDS + beg + t + 1]; int s_, d_; load_pair(pairs, (int)e_nxt, mode, s_, d_); d_nxt = (uint32_t)d_; }
      }
      const float4 av  = *(const float4*)&atoms[d * AD + jq * 4];
      const float4 b0v = *(const float4*)&bonds[e * BD + kk * 8];
      const float4 b1v = *(const float4*)&bonds[e * BD + kk * 8 + 4];
      RUP(R1, 0, b0v.x) RUP(R1, 1, b0v.y) RUP(R1, 2, b0v.z) RUP(R1, 3, b0v.w)
      RUP(R1, 4, b1v.x) RUP(R1, 5, b1v.y) RUP(R1, 6, b1v.z) RUP(R1, 7, b1v.w)
      if (kk == 0){ S1.x += av.x; S1.y += av.y; S1.z += av.z; S1.w += av.w; }
    }
  }

  // ---- contraction, i split into two halves (acc = 16/atom live per half) ----
  float* myred = &red[wid * 520];
  for (int half = 0; half < 2; ++half){
    float aA[16], aB[16];
    #pragma unroll
    for (int i = 0; i < 16; ++i){ aA[i] = 0.f; aB[i] = 0.f; }

    #pragma unroll
    for (int c = 0; c < 8; ++c){
      __syncthreads();
      #pragma unroll
      for (int q = 0; q < 4; ++q){
        const int idx   = tid + q * 256;       // 0..1023 float4s
        const int slot  = idx >> 7;            // 0..7
        const int col16 = idx & 127;
        *(float4*)&Ksh[(slot * 128 + (col16 ^ (slot << 3))) * 4] =
          *(const float4*)&Kg[(slot * 8 + c) * 1024 + half * 512 + col16 * 4];
      }
      __syncthreads();
      #pragma unroll
      for (int i = 0; i < 16; ++i){
        const float4 kv = *(const float4*)&Ksh[(kk * 128 + ((i * 8 + jq) ^ (kk << 3))) * 4];
        aA[i] += kv.x * R0[c][0] + kv.y * R0[c][1] + kv.z * R0[c][2] + kv.w * R0[c][3];
        aB[i] += kv.x * R1[c][0] + kv.y * R1[c][1] + kv.z * R1[c][2] + kv.w * R1[c][3];
      }
    }

    // bias via S on kk==0 lanes (counted once by the transpose-reduce)
    if (kk == 0){
      #pragma unroll
      for (int i = 0; i < 16; ++i){
        const float4 bv = *(const float4*)&bias[(half * 16 + i) * 32 + jq * 4];
        aA[i] += bv.x * S0.x + bv.y * S0.y + bv.z * S0.z + bv.w * S0.w;
        aB[i] += bv.x * S1.x + bv.y * S1.y + bv.z * S1.z + bv.w * S1.w;
      }
    }

    EPI8(aA, 0, a0)
    EPI8(aA, 1, a0)
    EPI8(aB, 0, a1)
    EPI8(aB, 1, a1)
  }
}

extern "C" void kernel_launch(void* const* d_in, const int* in_sizes, int n_in,
                              void* d_out, int out_size, void* d_ws, size_t ws_size,
                              hipStream_t stream){
  const float* atoms = (const float*)d_in[0];
  const float* bonds = (const float*)d_in[1];
  const void*  pairs = d_in[2];
  const float* Kg    = (const float*)d_in[3];
  const float* bias  = (const float*)d_in[4];
  float* out = (float*)d_out;
  uint32_t* ws = (uint32_t*)d_ws;
  const int packed = (ws_size >= WS_NEED_PACKED) ? 1 : 0;

  hipMemsetAsync(ws + WS_COUNTS, 0, sizeof(uint32_t) * 2 * NA, stream);  // counts + cursor
  k_detect<<<1, 256, 0, stream>>>(pairs, ws);
  k_hist<<<(NE + 255) / 256, 256, 0, stream>>>(pairs, ws);
  k_scan<<<1, 1024, 0, stream>>>(ws);
  if (packed) k_scatter<1><<<(NE + 255) / 256, 256, 0, stream>>>(pairs, ws);
  else        k_scatter<0><<<(NE + 255) / 256, 256, 0, stream>>>(pairs, ws);
  k_main<<<NA / 8, 256, 0, stream>>>(atoms, bonds, pairs, Kg, bias, out, ws, packed);
}

// Round 8
// 1235.932 us; speedup vs baseline: 2.9009x; 2.9009x over previous
//
#include <hip/hip_runtime.h>
#include <stdint.h>

#define NA 50000
#define NE 320000
#define AD 32
#define BD 64

// workspace layout (uint32 slots)
#define WS_FLAG   0
#define WS_COUNTS 16
#define WS_CURSOR (WS_COUNTS + NA)           // 50016
#define WS_OFFS   (WS_CURSOR + NA)           // 100016, NA+1 entries
#define WS_EIDS   150048                     // 8B-aligned; packed: uint2[NE], unpacked: u32[NE]
#define WS_NEED_PACKED   ((size_t)(WS_EIDS + 2 * NE) * 4)

__device__ __forceinline__ void load_pair(const void* p, int e, int mode, int& s, int& d){
  if (mode){ const int* q = (const int*)p; s = q[2*e]; d = q[2*e+1]; }
  else     { const long long* q = (const long long*)p; s = (int)q[2*e]; d = (int)q[2*e+1]; }
}

// detect int32 vs int64 pair_indices: int64 -> odd 32-bit words all 0 (values < 50000)
__global__ void k_detect(const void* pairs, uint32_t* ws){
  const uint32_t* w = (const uint32_t*)pairs;
  uint32_t x = 0;
  for (int i = threadIdx.x; i < 2048; i += 256) x |= w[2*i + 1];
  __shared__ uint32_t sh[256];
  sh[threadIdx.x] = x; __syncthreads();
  for (int s = 128; s > 0; s >>= 1){
    if (threadIdx.x < s) sh[threadIdx.x] |= sh[threadIdx.x + s];
    __syncthreads();
  }
  if (threadIdx.x == 0) ws[WS_FLAG] = (sh[0] != 0u) ? 1u : 0u;  // 1 = int32 mode
}

__global__ void k_hist(const void* pairs, uint32_t* ws){
  int e = blockIdx.x * 256 + threadIdx.x;
  if (e >= NE) return;
  int mode = (int)ws[WS_FLAG];
  int s, d; load_pair(pairs, e, mode, s, d);
  atomicAdd(&ws[WS_COUNTS + s], 1u);
}

// single-block exclusive scan of counts[NA] -> offs[NA+1]
__global__ void k_scan(uint32_t* ws){
  const uint32_t* counts = ws + WS_COUNTS;
  uint32_t* offs = ws + WS_OFFS;
  __shared__ uint32_t wsum[16];
  __shared__ uint32_t carrysh;
  const int tid = threadIdx.x; const int lane = tid & 63; const int wid = tid >> 6;
  if (tid == 0) carrysh = 0u;
  __syncthreads();
  for (int base = 0; base < NA; base += 8192){
    uint32_t v[8]; uint32_t tot = 0u;
    int i0 = base + tid * 8;
    #pragma unroll
    for (int j = 0; j < 8; ++j){ int i = i0 + j; v[j] = (i < NA) ? counts[i] : 0u; tot += v[j]; }
    uint32_t inc = tot;
    #pragma unroll
    for (int m = 1; m < 64; m <<= 1){ uint32_t t = __shfl_up(inc, m); if (lane >= m) inc += t; }
    if (lane == 63) wsum[wid] = inc;
    __syncthreads();
    if (wid == 0){
      uint32_t w = (lane < 16) ? wsum[lane] : 0u;
      #pragma unroll
      for (int m = 1; m < 16; m <<= 1){ uint32_t t = __shfl_up(w, m); if (lane >= m) w += t; }
      if (lane < 16) wsum[lane] = w;     // inclusive over waves
    }
    __syncthreads();
    uint32_t waveoff = (wid == 0) ? 0u : wsum[wid - 1];
    uint32_t run = carrysh + waveoff + (inc - tot);
    #pragma unroll
    for (int j = 0; j < 8; ++j){ int i = i0 + j; if (i < NA) offs[i] = run; run += v[j]; }
    __syncthreads();
    if (tid == 0) carrysh += wsum[15];
    __syncthreads();
  }
  if (tid == 0) offs[NA] = carrysh;
}

template<int PACKED>
__global__ void k_scatter(const void* pairs, uint32_t* ws){
  int e = blockIdx.x * 256 + threadIdx.x;
  if (e >= NE) return;
  int mode = (int)ws[WS_FLAG];
  int s, d; load_pair(pairs, e, mode, s, d);
  uint32_t p = atomicAdd(&ws[WS_CURSOR + s], 1u);
  uint32_t pos = ws[WS_OFFS + s] + p;
  if (PACKED) ((uint2*)(ws + WS_EIDS))[pos] = make_uint2((uint32_t)e, (uint32_t)d);
  else        ws[WS_EIDS + pos] = (uint32_t)e;
}

#define F4Z make_float4(0.f, 0.f, 0.f, 0.f)
#define FMA4(dst, v, s) { dst.x += (v).x*(s); dst.y += (v).y*(s); dst.z += (v).z*(s); dst.w += (v).w*(s); }
#define ADD4(dst, v)    { dst.x += (v).x; dst.y += (v).y; dst.z += (v).z; dst.w += (v).w; }

// edge loop for one atom: accumulates 8 named float4 R regs + S
#define EDGE_LOOP(A, Q0,Q1,Q2,Q3,Q4,Q5,Q6,Q7, SS)                                   \
  { const uint32_t beg = offs[A], endv = offs[(A)+1];                               \
    for (uint32_t t = beg; t < endv; ++t){                                          \
      uint32_t e_, d_;                                                              \
      if (PACKED){ const uint2 ed = eds[t]; e_ = ed.x; d_ = ed.y; }                 \
      else { e_ = eids[t]; int ss_, dd_; load_pair(pairs, (int)e_, mode, ss_, dd_); d_ = (uint32_t)dd_; } \
      const float4 av  = *(const float4*)&atoms[d_ * AD + jq * 4];                  \
      const float4 b0v = *(const float4*)&bonds[e_ * BD + kk * 8];                  \
      const float4 b1v = *(const float4*)&bonds[e_ * BD + kk * 8 + 4];              \
      FMA4(Q0, av, b0v.x) FMA4(Q1, av, b0v.y) FMA4(Q2, av, b0v.z) FMA4(Q3, av, b0v.w) \
      FMA4(Q4, av, b1v.x) FMA4(Q5, av, b1v.y) FMA4(Q6, av, b1v.z) FMA4(Q7, av, b1v.w) \
      if (kk == 0) ADD4(SS, av)                                                     \
    } }

#define COMP0 x
#define COMP1 y
#define COMP2 z
#define COMP3 w
#define CDOT(acc, comp, kv, r) acc.comp += (kv).x*(r).x + (kv).y*(r).y + (kv).z*(r).z + (kv).w*(r).w;

// one (c, i) contraction step: K row (kk*8+c), output i = h*16 + g*4 + io
#define CSTEP(c, h, g, io)                                                          \
  { const float4 kv = *(const float4*)&Kg[(kk*8+(c))*1024 + (h)*512 + ((g)*4+(io))*32 + jq*4]; \
    CDOT(aA##g, COMP##io, kv, r0_##c) CDOT(aB##g, COMP##io, kv, r1_##c) }
#define CSTEP4(c, h, g)  CSTEP(c,h,g,0) CSTEP(c,h,g,1) CSTEP(c,h,g,2) CSTEP(c,h,g,3)
#define CBLOCK(c, h)     CSTEP4(c,h,0) CSTEP4(c,h,1) CSTEP4(c,h,2) CSTEP4(c,h,3)
#define CONTRACT_ALLC(h) CBLOCK(0,h) CBLOCK(1,h) CBLOCK(2,h) CBLOCK(3,h) \
                         CBLOCK(4,h) CBLOCK(5,h) CBLOCK(6,h) CBLOCK(7,h)

#define BSTEP(h, g, io)                                                             \
  { const float4 bv = *(const float4*)&bias[((h)*16+(g)*4+(io))*32 + jq*4];         \
    CDOT(aA##g, COMP##io, bv, S0) CDOT(aB##g, COMP##io, bv, S1) }
#define BSTEP4(h, g) BSTEP(h,g,0) BSTEP(h,g,1) BSTEP(h,g,2) BSTEP(h,g,3)
#define BIAS_ALL(h)  BSTEP4(h,0) BSTEP4(h,1) BSTEP4(h,2) BSTEP4(h,3)

// per-wave transpose-reduce of 8 acc components (v0,v1) -> out[a,32..], group g, half h
#define EPI8(v0, v1, g, h, a)                                                       \
  { myred[0*65+lane]=v0.x; myred[1*65+lane]=v0.y; myred[2*65+lane]=v0.z; myred[3*65+lane]=v0.w; \
    myred[4*65+lane]=v1.x; myred[5*65+lane]=v1.y; myred[6*65+lane]=v1.z; myred[7*65+lane]=v1.w; \
    const int ii2 = lane & 7, seg = lane >> 3;                                      \
    float p = myred[ii2*65+seg*8+0] + myred[ii2*65+seg*8+1] + myred[ii2*65+seg*8+2] \
            + myred[ii2*65+seg*8+3] + myred[ii2*65+seg*8+4] + myred[ii2*65+seg*8+5] \
            + myred[ii2*65+seg*8+6] + myred[ii2*65+seg*8+7];                        \
    p += __shfl_xor(p, 8); p += __shfl_xor(p, 16); p += __shfl_xor(p, 32);          \
    if (lane < 8) out[(a)*32 + (h)*16 + (g)*8 + lane] = p; }

#define CONTRACT_HALF(h)                                                            \
  { float4 aA0=F4Z, aA1=F4Z, aA2=F4Z, aA3=F4Z;                                      \
    float4 aB0=F4Z, aB1=F4Z, aB2=F4Z, aB3=F4Z;                                      \
    CONTRACT_ALLC(h)                                                                \
    if (kk == 0){ BIAS_ALL(h) }                                                     \
    EPI8(aA0, aA1, 0, h, a0) EPI8(aA2, aA3, 1, h, a0)                               \
    EPI8(aB0, aB1, 0, h, a1) EPI8(aB2, aB3, 1, h, a1) }

// 256 threads = 4 waves, 2 atoms/wave, grid = NA/8 = 6250. No barriers, no K-LDS.
// lane = (kk = lane&7, jq = lane>>3). r{sel}_c = R[k = kk*8+c][j = jq*4 .. +3].
// All per-lane state in NAMED float4 vars (no indexed locals -> no scratch demotion).
template<int PACKED>
__launch_bounds__(256, 1)
__global__ void k_main(const float* __restrict__ atoms, const float* __restrict__ bonds,
                       const void* __restrict__ pairs, const float* __restrict__ Kg,
                       const float* __restrict__ bias, float* __restrict__ out,
                       const uint32_t* __restrict__ ws){
  __shared__ float red[4 * 520];        // per-wave transpose scratch only

  const int tid  = threadIdx.x;
  const int lane = tid & 63;
  const int wid  = tid >> 6;            // 0..3
  const int kk   = lane & 7;
  const int jq   = lane >> 3;           // 0..7
  const int mode = (int)ws[WS_FLAG];
  const uint32_t* offs = ws + WS_OFFS;
  const uint32_t* eids = ws + WS_EIDS;
  const uint2*    eds  = (const uint2*)(ws + WS_EIDS);
  (void)mode; (void)eids; (void)eds;

  const int a0 = blockIdx.x * 8 + wid * 2;
  const int a1 = a0 + 1;

  float4 r0_0=F4Z, r0_1=F4Z, r0_2=F4Z, r0_3=F4Z, r0_4=F4Z, r0_5=F4Z, r0_6=F4Z, r0_7=F4Z;
  float4 r1_0=F4Z, r1_1=F4Z, r1_2=F4Z, r1_3=F4Z, r1_4=F4Z, r1_5=F4Z, r1_6=F4Z, r1_7=F4Z;
  float4 S0=F4Z, S1=F4Z;

  EDGE_LOOP(a0, r0_0,r0_1,r0_2,r0_3,r0_4,r0_5,r0_6,r0_7, S0)
  EDGE_LOOP(a1, r1_0,r1_1,r1_2,r1_3,r1_4,r1_5,r1_6,r1_7, S1)

  float* myred = &red[wid * 520];
  CONTRACT_HALF(0)
  CONTRACT_HALF(1)
}

extern "C" void kernel_launch(void* const* d_in, const int* in_sizes, int n_in,
                              void* d_out, int out_size, void* d_ws, size_t ws_size,
                              hipStream_t stream){
  const float* atoms = (const float*)d_in[0];
  const float* bonds = (const float*)d_in[1];
  const void*  pairs = d_in[2];
  const float* Kg    = (const float*)d_in[3];
  const float* bias  = (const float*)d_in[4];
  float* out = (float*)d_out;
  uint32_t* ws = (uint32_t*)d_ws;
  const int packed = (ws_size >= WS_NEED_PACKED) ? 1 : 0;

  hipMemsetAsync(ws + WS_COUNTS, 0, sizeof(uint32_t) * 2 * NA, stream);  // counts + cursor
  k_detect<<<1, 256, 0, stream>>>(pairs, ws);
  k_hist<<<(NE + 255) / 256, 256, 0, stream>>>(pairs, ws);
  k_scan<<<1, 1024, 0, stream>>>(ws);
  if (packed){
    k_scatter<1><<<(NE + 255) / 256, 256, 0, stream>>>(pairs, ws);
    k_main<1><<<NA / 8, 256, 0, stream>>>(atoms, bonds, pairs, Kg, bias, out, ws);
  } else {
    k_scatter<0><<<(NE + 255) / 256, 256, 0, stream>>>(pairs, ws);
    k_main<0><<<NA / 8, 256, 0, stream>>>(atoms, bonds, pairs, Kg, bias, out, ws);
  }
}

// Round 10
// 962.110 us; speedup vs baseline: 3.7265x; 1.2846x over previous
//
#include <hip/hip_runtime.h>
#include <stdint.h>

#define NA 50000
#define NE 320000
#define AD 32
#define BD 64
#define PADROW 516   // 512 + 4-float pad: stage writes & b128 reads both conflict-free

// workspace layout (uint32 slots)
#define WS_FLAG   0
#define WS_COUNTS 16
#define WS_CURSOR (WS_COUNTS + NA)           // 50016
#define WS_OFFS   (WS_CURSOR + NA)           // 100016, NA+1 entries
#define WS_EIDS   150048                     // 8B-aligned; packed: uint2[NE], unpacked: u32[NE]
#define WS_NEED_PACKED   ((size_t)(WS_EIDS + 2 * NE) * 4)

__device__ __forceinline__ void load_pair(const void* p, int e, int mode, int& s, int& d){
  if (mode){ const int* q = (const int*)p; s = q[2*e]; d = q[2*e+1]; }
  else     { const long long* q = (const long long*)p; s = (int)q[2*e]; d = (int)q[2*e+1]; }
}

// detect int32 vs int64 pair_indices: int64 -> odd 32-bit words all 0 (values < 50000)
__global__ void k_detect(const void* pairs, uint32_t* ws){
  const uint32_t* w = (const uint32_t*)pairs;
  uint32_t x = 0;
  for (int i = threadIdx.x; i < 2048; i += 256) x |= w[2*i + 1];
  __shared__ uint32_t sh[256];
  sh[threadIdx.x] = x; __syncthreads();
  for (int s = 128; s > 0; s >>= 1){
    if (threadIdx.x < s) sh[threadIdx.x] |= sh[threadIdx.x + s];
    __syncthreads();
  }
  if (threadIdx.x == 0) ws[WS_FLAG] = (sh[0] != 0u) ? 1u : 0u;  // 1 = int32 mode
}

__global__ void k_hist(const void* pairs, uint32_t* ws){
  int e = blockIdx.x * 256 + threadIdx.x;
  if (e >= NE) return;
  int mode = (int)ws[WS_FLAG];
  int s, d; load_pair(pairs, e, mode, s, d);
  atomicAdd(&ws[WS_COUNTS + s], 1u);
}

// single-block exclusive scan of counts[NA] -> offs[NA+1]
__global__ void k_scan(uint32_t* ws){
  const uint32_t* counts = ws + WS_COUNTS;
  uint32_t* offs = ws + WS_OFFS;
  __shared__ uint32_t wsum[16];
  __shared__ uint32_t carrysh;
  const int tid = threadIdx.x; const int lane = tid & 63; const int wid = tid >> 6;
  if (tid == 0) carrysh = 0u;
  __syncthreads();
  for (int base = 0; base < NA; base += 8192){
    uint32_t v[8]; uint32_t tot = 0u;
    int i0 = base + tid * 8;
    #pragma unroll
    for (int j = 0; j < 8; ++j){ int i = i0 + j; v[j] = (i < NA) ? counts[i] : 0u; tot += v[j]; }
    uint32_t inc = tot;
    #pragma unroll
    for (int m = 1; m < 64; m <<= 1){ uint32_t t = __shfl_up(inc, m); if (lane >= m) inc += t; }
    if (lane == 63) wsum[wid] = inc;
    __syncthreads();
    if (wid == 0){
      uint32_t w = (lane < 16) ? wsum[lane] : 0u;
      #pragma unroll
      for (int m = 1; m < 16; m <<= 1){ uint32_t t = __shfl_up(w, m); if (lane >= m) w += t; }
      if (lane < 16) wsum[lane] = w;     // inclusive over waves
    }
    __syncthreads();
    uint32_t waveoff = (wid == 0) ? 0u : wsum[wid - 1];
    uint32_t run = carrysh + waveoff + (inc - tot);
    #pragma unroll
    for (int j = 0; j < 8; ++j){ int i = i0 + j; if (i < NA) offs[i] = run; run += v[j]; }
    __syncthreads();
    if (tid == 0) carrysh += wsum[15];
    __syncthreads();
  }
  if (tid == 0) offs[NA] = carrysh;
}

template<int PACKED>
__global__ void k_scatter(const void* pairs, uint32_t* ws){
  int e = blockIdx.x * 256 + threadIdx.x;
  if (e >= NE) return;
  int mode = (int)ws[WS_FLAG];
  int s, d; load_pair(pairs, e, mode, s, d);
  uint32_t p = atomicAdd(&ws[WS_CURSOR + s], 1u);
  uint32_t pos = ws[WS_OFFS + s] + p;
  if (PACKED) ((uint2*)(ws + WS_EIDS))[pos] = make_uint2((uint32_t)e, (uint32_t)d);
  else        ws[WS_EIDS + pos] = (uint32_t)e;
}

#define F4Z make_float4(0.f, 0.f, 0.f, 0.f)
#define FMA4(dst, v, s) { dst.x += (v).x*(s); dst.y += (v).y*(s); dst.z += (v).z*(s); dst.w += (v).w*(s); }
#define ADD4(dst, v)    { dst.x += (v).x; dst.y += (v).y; dst.z += (v).z; dst.w += (v).w; }

// edge loop for one atom, software-pipelined: ids 2-ahead, data 1-ahead; named vars only
#define EDGE_LOOP_P(A, Q0,Q1,Q2,Q3,Q4,Q5,Q6,Q7, SS)                                 \
  { const uint32_t beg = offs[A]; const uint32_t n = offs[(A)+1] - beg;             \
    uint32_t e1_ = 0, d1_ = 0; float4 av = F4Z, b0v = F4Z, b1v = F4Z;               \
    if (n){ uint32_t e0_, d0_;                                                      \
      if (PACKED){ const uint2 t0_ = eds[beg]; e0_ = t0_.x; d0_ = t0_.y; }          \
      else { e0_ = eids[beg]; int s_, d_; load_pair(pairs, (int)e0_, mode, s_, d_); d0_ = (uint32_t)d_; } \
      av  = *(const float4*)&atoms[d0_ * AD + jq * 4];                              \
      b0v = *(const float4*)&bonds[e0_ * BD + kk * 8];                              \
      b1v = *(const float4*)&bonds[e0_ * BD + kk * 8 + 4];                          \
      if (n > 1){                                                                   \
        if (PACKED){ const uint2 t1_ = eds[beg + 1]; e1_ = t1_.x; d1_ = t1_.y; }    \
        else { e1_ = eids[beg + 1]; int s_, d_; load_pair(pairs, (int)e1_, mode, s_, d_); d1_ = (uint32_t)d_; } } } \
    for (uint32_t t = 0; t < n; ++t){                                               \
      float4 avn = F4Z, b0n = F4Z, b1n = F4Z;                                       \
      if (t + 1 < n){ avn = *(const float4*)&atoms[d1_ * AD + jq * 4];              \
                      b0n = *(const float4*)&bonds[e1_ * BD + kk * 8];              \
                      b1n = *(const float4*)&bonds[e1_ * BD + kk * 8 + 4]; }        \
      uint32_t e2_ = 0, d2_ = 0;                                                    \
      if (t + 2 < n){                                                               \
        if (PACKED){ const uint2 t2_ = eds[beg + t + 2]; e2_ = t2_.x; d2_ = t2_.y; }\
        else { e2_ = eids[beg + t + 2]; int s_, d_; load_pair(pairs, (int)e2_, mode, s_, d_); d2_ = (uint32_t)d_; } } \
      FMA4(Q0, av, b0v.x) FMA4(Q1, av, b0v.y) FMA4(Q2, av, b0v.z) FMA4(Q3, av, b0v.w) \
      FMA4(Q4, av, b1v.x) FMA4(Q5, av, b1v.y) FMA4(Q6, av, b1v.z) FMA4(Q7, av, b1v.w) \
      if (kk == 0) ADD4(SS, av)                                                     \
      av = avn; b0v = b0n; b1v = b1n; e1_ = e2_; d1_ = d2_;                         \
    } }

// stage K chunk for step s (half = s>>3, c = s&7) into buffer (s&1); coalesced
#define STAGE(s) {                                                                  \
  float* dst = &Ksh[((s)&1) * (8 * PADROW)];                                        \
  _Pragma("unroll")                                                                 \
  for (int q = 0; q < 4; ++q){                                                      \
    const int idx = tid + q * 256; const int row = idx >> 7; const int cf = idx & 127; \
    *(float4*)&dst[row * PADROW + cf * 4] =                                         \
      *(const float4*)&Kg[(row * 8 + ((s)&7)) * 1024 + ((s)>>3) * 512 + cf * 4]; } }

#define COMP0 x
#define COMP1 y
#define COMP2 z
#define COMP3 w
#define CDOT(acc, comp, kv, r) acc.comp += (kv).x*(r).x + (kv).y*(r).y + (kv).z*(r).z + (kv).w*(r).w;

#define CSTEPL(c, g, io) { const float4 kv = *(const float4*)&kb[kk * PADROW + ((g)*4+(io))*32 + jq*4]; \
  CDOT(aA##g, COMP##io, kv, r0_##c) CDOT(aB##g, COMP##io, kv, r1_##c) }
#define CB4(c, g) CSTEPL(c,g,0) CSTEPL(c,g,1) CSTEPL(c,g,2) CSTEPL(c,g,3)
#define CBLK(c)   CB4(c,0) CB4(c,1) CB4(c,2) CB4(c,3)

// one pipeline step: prefetch-stage s+1 into other buffer, compute c from buffer (s&1)
#define DOSTEP(s, c) {                                                              \
  if ((s) < 15) STAGE((s)+1)                                                        \
  const float* kb = &Ksh[((s)&1) * (8 * PADROW)];                                   \
  CBLK(c)                                                                           \
  __syncthreads(); }

#define BSTEP(h, g, io)                                                             \
  { const float4 bv = *(const float4*)&bias[((h)*16+(g)*4+(io))*32 + jq*4];         \
    CDOT(aA##g, COMP##io, bv, S0) CDOT(aB##g, COMP##io, bv, S1) }
#define BSTEP4(h, g) BSTEP(h,g,0) BSTEP(h,g,1) BSTEP(h,g,2) BSTEP(h,g,3)
#define BIAS_ALL(h)  BSTEP4(h,0) BSTEP4(h,1) BSTEP4(h,2) BSTEP4(h,3)

// per-wave transpose-reduce of 8 acc components -> out[a*32 + h*16 + g*8 + 0..7]
#define EPI8(v0, v1, g, h, a)                                                       \
  { myred[0*65+lane]=v0.x; myred[1*65+lane]=v0.y; myred[2*65+lane]=v0.z; myred[3*65+lane]=v0.w; \
    myred[4*65+lane]=v1.x; myred[5*65+lane]=v1.y; myred[6*65+lane]=v1.z; myred[7*65+lane]=v1.w; \
    const int ii2 = lane & 7, seg = lane >> 3;                                      \
    float p = myred[ii2*65+seg*8+0] + myred[ii2*65+seg*8+1] + myred[ii2*65+seg*8+2] \
            + myred[ii2*65+seg*8+3] + myred[ii2*65+seg*8+4] + myred[ii2*65+seg*8+5] \
            + myred[ii2*65+seg*8+6] + myred[ii2*65+seg*8+7];                        \
    p += __shfl_xor(p, 8); p += __shfl_xor(p, 16); p += __shfl_xor(p, 32);          \
    if (lane < 8) out[(a)*32 + (h)*16 + (g)*8 + lane] = p; }

// 256 threads = 4 waves, 2 atoms/wave, grid = NA/8 = 6250.
// lane = (kk = lane&7, jq = lane>>3). r{sel}_c = R[k = kk*8+c][j = jq*4 .. +3].
// K staged in double-buffered LDS (8x516 padded rows), 1 barrier/step.
// All per-lane state in NAMED float4 vars (no indexed locals -> no scratch demotion).
template<int PACKED>
__launch_bounds__(256, 1)
__global__ void k_main(const float* __restrict__ atoms, const float* __restrict__ bonds,
                       const void* __restrict__ pairs, const float* __restrict__ Kg,
                       const float* __restrict__ bias, float* __restrict__ out,
                       const uint32_t* __restrict__ ws){
  __shared__ float Ksh[2 * 8 * PADROW];   // 33 KB double-buffered K chunk
  __shared__ float red[4 * 520];          // per-wave transpose scratch

  const int tid  = threadIdx.x;
  const int lane = tid & 63;
  const int wid  = tid >> 6;            // 0..3
  const int kk   = lane & 7;
  const int jq   = lane >> 3;           // 0..7
  const int mode = (int)ws[WS_FLAG];
  const uint32_t* offs = ws + WS_OFFS;
  const uint32_t* eids = ws + WS_EIDS;
  const uint2*    eds  = (const uint2*)(ws + WS_EIDS);
  (void)mode; (void)eids; (void)eds;

  const int a0 = blockIdx.x * 8 + wid * 2;
  const int a1 = a0 + 1;

  float4 r0_0=F4Z, r0_1=F4Z, r0_2=F4Z, r0_3=F4Z, r0_4=F4Z, r0_5=F4Z, r0_6=F4Z, r0_7=F4Z;
  float4 r1_0=F4Z, r1_1=F4Z, r1_2=F4Z, r1_3=F4Z, r1_4=F4Z, r1_5=F4Z, r1_6=F4Z, r1_7=F4Z;
  float4 S0=F4Z, S1=F4Z;

  EDGE_LOOP_P(a0, r0_0,r0_1,r0_2,r0_3,r0_4,r0_5,r0_6,r0_7, S0)
  EDGE_LOOP_P(a1, r1_0,r1_1,r1_2,r1_3,r1_4,r1_5,r1_6,r1_7, S1)

  float* myred = &red[wid * 520];

  STAGE(0)
  __syncthreads();

  { // half 0: output i = 0..15
    float4 aA0=F4Z, aA1=F4Z, aA2=F4Z, aA3=F4Z;
    float4 aB0=F4Z, aB1=F4Z, aB2=F4Z, aB3=F4Z;
    DOSTEP(0,0) DOSTEP(1,1) DOSTEP(2,2) DOSTEP(3,3)
    DOSTEP(4,4) DOSTEP(5,5) DOSTEP(6,6) DOSTEP(7,7)
    if (kk == 0){ BIAS_ALL(0) }
    EPI8(aA0, aA1, 0, 0, a0) EPI8(aA2, aA3, 1, 0, a0)
    EPI8(aB0, aB1, 0, 0, a1) EPI8(aB2, aB3, 1, 0, a1)
  }
  { // half 1: output i = 16..31
    float4 aA0=F4Z, aA1=F4Z, aA2=F4Z, aA3=F4Z;
    float4 aB0=F4Z, aB1=F4Z, aB2=F4Z, aB3=F4Z;
    DOSTEP(8,0) DOSTEP(9,1) DOSTEP(10,2) DOSTEP(11,3)
    DOSTEP(12,4) DOSTEP(13,5) DOSTEP(14,6) DOSTEP(15,7)
    if (kk == 0){ BIAS_ALL(1) }
    EPI8(aA0, aA1, 0, 1, a0) EPI8(aA2, aA3, 1, 1, a0)
    EPI8(aB0, aB1, 0, 1, a1) EPI8(aB2, aB3, 1, 1, a1)
  }
}

extern "C" void kernel_launch(void* const* d_in, const int* in_sizes, int n_in,
                              void* d_out, int out_size, void* d_ws, size_t ws_size,
                              hipStream_t stream){
  const float* atoms = (const float*)d_in[0];
  const float* bonds = (const float*)d_in[1];
  const void*  pairs = d_in[2];
  const float* Kg    = (const float*)d_in[3];
  const float* bias  = (const float*)d_in[4];
  float* out = (float*)d_out;
  uint32_t* ws = (uint32_t*)d_ws;
  const int packed = (ws_size >= WS_NEED_PACKED) ? 1 : 0;

  hipMemsetAsync(ws + WS_COUNTS, 0, sizeof(uint32_t) * 2 * NA, stream);  // counts + cursor
  k_detect<<<1, 256, 0, stream>>>(pairs, ws);
  k_hist<<<(NE + 255) / 256, 256, 0, stream>>>(pairs, ws);
  k_scan<<<1, 1024, 0, stream>>>(ws);
  if (packed){
    k_scatter<1><<<(NE + 255) / 256, 256, 0, stream>>>(pairs, ws);
    k_main<1><<<NA / 8, 256, 0, stream>>>(atoms, bonds, pairs, Kg, bias, out, ws);
  } else {
    k_scatter<0><<<(NE + 255) / 256, 256, 0, stream>>>(pairs, ws);
    k_main<0><<<NA / 8, 256, 0, stream>>>(atoms, bonds, pairs, Kg, bias, out, ws);
  }
}